// Round 2
// baseline (1722.931 us; speedup 1.0000x reference)
//
#include <hip/hip_runtime.h>

// Problem constants
#define TT 20
#define NNODE 512
#define G2C 16
#define RCH 128
#define ECH 64
#define ICH 2
#define OCH 5
#define KSOC 8192          // N*G2
#define KSPLIT 16
#define KCH 512            // KSOC/KSPLIT

// workspace layout (double offsets)
#define OFF_H    0u         // [512*128]
#define OFF_C    65536u     // [512*128]
#define OFF_HT   131072u    // Ht[k=8192][e=64]
#define OFF_PART 655360u    // part[16][512][64]
#define OFF_WGT  1179648u   // WgT[p=128][r=128][q=4]
#define OFF_WHT  1245184u   // WhT[p=128][r=128][q=4]
#define OFF_WTT  1310720u   // WtT[q2=2048][e=64]
#define OFF_BS   1441792u   // bsum[r=128][q=4]
// total 1442304 doubles = 11.54 MB

__device__ __forceinline__ double sigd(double x){ return 1.0/(1.0+exp(-x)); }

__global__ void k_init(const float* __restrict__ h0, const float* __restrict__ c0,
                       const float* __restrict__ W_ih, const float* __restrict__ b_ih,
                       const float* __restrict__ W_hh, const float* __restrict__ b_hh,
                       const float* __restrict__ W_tensor, double* __restrict__ ws) {
  int tid = blockIdx.x*blockDim.x + threadIdx.x;
  int nthr = gridDim.x*blockDim.x;
  double* h = ws + OFF_H; double* c = ws + OFF_C;
  double* WgT = ws + OFF_WGT; double* WhT = ws + OFF_WHT;
  double* WtT = ws + OFF_WTT; double* bs = ws + OFF_BS;
  for (int i = tid; i < NNODE*RCH; i += nthr) { h[i] = (double)h0[i]; c[i] = (double)c0[i]; }
  // WgT[(p*128+r)*4+q] = W_ih[(q*128+r)*128+p]  (gate order i,f,g,o)
  for (int i = tid; i < 65536; i += nthr) {
    int q = i & 3; int pr = i >> 2; int r = pr & 127; int p = pr >> 7;
    WgT[i] = (double)W_ih[(q*128 + r)*128 + p];
    WhT[i] = (double)W_hh[(q*128 + r)*128 + p];
  }
  // WtT[q2*64+e] = W_tensor[e*2048+q2],  q2 = g*128+r
  for (int i = tid; i < 131072; i += nthr) {
    int e = i & 63; int q2 = i >> 6;
    WtT[i] = (double)W_tensor[e*2048 + q2];
  }
  for (int i = tid; i < 512; i += nthr) {
    int q = i & 3; int r = i >> 2;
    bs[i] = (double)b_ih[q*128 + r] + (double)b_hh[q*128 + r];
  }
}

// Ht[m*16+g][e] = sum_r h[m,r] * W_tensor[e, g*128+r]   (t=0 only; later fused in k_cell)
__global__ __launch_bounds__(256) void k_ht(double* __restrict__ ws) {
  __shared__ double hb[2][128];
  const double* __restrict__ h = ws + OFF_H;
  const double* __restrict__ WtT = ws + OFF_WTT;
  double* __restrict__ Ht = ws + OFF_HT;
  const int m0 = blockIdx.x << 1;
  const int tid = threadIdx.x;
  hb[tid>>7][tid&127] = h[(size_t)(m0 + (tid>>7))*RCH + (tid&127)];
  __syncthreads();
  const int e = tid & 63, gq = tid >> 6;
  double acc[2][4] = {};
  for (int rr = 0; rr < 128; ++rr) {
    double hv0 = hb[0][rr], hv1 = hb[1][rr];
    #pragma unroll
    for (int jg = 0; jg < 4; ++jg) {
      double wv = WtT[((size_t)(((gq<<2)+jg)*RCH + rr))*ECH + e];
      acc[0][jg] += hv0*wv; acc[1][jg] += hv1*wv;
    }
  }
  #pragma unroll
  for (int n2 = 0; n2 < 2; ++n2)
    #pragma unroll
    for (int jg = 0; jg < 4; ++jg)
      Ht[(((size_t)(m0+n2))*G2C + (gq<<2)+jg)*ECH + e] = acc[n2][jg];
}

// part[kc][n][e] = sum_{k in chunk kc} grid_flat[n,k] * Ht[k,e]
// 512 blocks = 32 n-groups(16 nodes) x 16 k-chunks; 4 waves split the 512-k chunk;
// cross-wave reduction in LDS so only 16 partials land in global.
__global__ __launch_bounds__(256) void k_social(const float* __restrict__ grids,
                                                double* __restrict__ ws, int t) {
  __shared__ __align__(16) double sgd[16*260];     // aliased: f32 grid tile, then f64 reduction
  float* sgf = (float*)sgd;                        // sg(row,col) = sgf[row*520+col]
  const double* __restrict__ Ht = ws + OFF_HT;
  double* __restrict__ part = ws + OFF_PART;
  const int kc = blockIdx.x & (KSPLIT-1);
  const int n0 = (blockIdx.x >> 4) << 4;
  const int kb = kc * KCH;
  const int tid = threadIdx.x;
  const float* gbase = grids + (size_t)t*NNODE*KSOC;
  for (int i = tid; i < 16*128; i += 256) {
    int row = i >> 7; int c4 = i & 127;
    float4 v = *(const float4*)(gbase + (size_t)(n0+row)*KSOC + kb + (c4<<2));
    *(float4*)(&sgf[row*520 + (c4<<2)]) = v;
  }
  __syncthreads();
  const int lane = tid & 63;
  const int wv = tid >> 6;
  const int e0 = (lane & 15) << 2;
  const int nq = lane >> 4;
  double acc[4][4] = {};
  const int kl0 = wv << 7;
  const double* htp = Ht + (size_t)(kb + kl0)*ECH + e0;
  for (int kk = 0; kk < 128; ++kk) {
    double2 b01 = *(const double2*)(htp + (size_t)kk*ECH);
    double2 b23 = *(const double2*)(htp + (size_t)kk*ECH + 2);
    const int kl = kl0 + kk;
    #pragma unroll
    for (int jn = 0; jn < 4; ++jn) {
      double av = (double)sgf[((jn<<2)+nq)*520 + kl];
      acc[jn][0] += av*b01.x; acc[jn][1] += av*b01.y;
      acc[jn][2] += av*b23.x; acc[jn][3] += av*b23.y;
    }
  }
  __syncthreads();                 // everyone done reading sgf
  if (wv > 0) {
    double* rp = sgd + ((size_t)(wv-1)*64 + lane)*16;
    #pragma unroll
    for (int jn = 0; jn < 4; ++jn)
      #pragma unroll
      for (int je = 0; je < 4; ++je) rp[(jn<<2)+je] = acc[jn][je];
  }
  __syncthreads();
  if (wv == 0) {
    #pragma unroll
    for (int w = 0; w < 3; ++w) {
      const double* rp = sgd + ((size_t)w*64 + lane)*16;
      #pragma unroll
      for (int jn = 0; jn < 4; ++jn)
        #pragma unroll
        for (int je = 0; je < 4; ++je) acc[jn][je] += rp[(jn<<2)+je];
    }
    #pragma unroll
    for (int jn = 0; jn < 4; ++jn) {
      double* pp = part + ((size_t)kc*NNODE + n0 + (jn<<2) + nq)*ECH + e0;
      pp[0]=acc[jn][0]; pp[1]=acc[jn][1]; pp[2]=acc[jn][2]; pp[3]=acc[jn][3];
    }
  }
}

// Per-node cell: te/ie -> gates -> LSTM pointwise -> out; then Ht for next step.
// 256 blocks x 2 nodes, 256 threads (128 per node, one r each).
__global__ __launch_bounds__(256) void k_cell(const float* __restrict__ nodes,
    const float* __restrict__ W_in, const float* __restrict__ b_in,
    const float* __restrict__ b_tensor,
    const float* __restrict__ W_out, const float* __restrict__ b_out,
    double* __restrict__ ws, float* __restrict__ outp,
    float* __restrict__ hf, float* __restrict__ cf, int t) {
  __shared__ double xbuf[2][128];
  __shared__ double hbuf[2][128];
  __shared__ double h2buf[2][128];
  double* __restrict__ h = ws + OFF_H;
  double* __restrict__ c = ws + OFF_C;
  double* __restrict__ Ht = ws + OFF_HT;
  const double* __restrict__ part = ws + OFF_PART;
  const double* __restrict__ WgT = ws + OFF_WGT;
  const double* __restrict__ WhT = ws + OFF_WHT;
  const double* __restrict__ WtT = ws + OFF_WTT;
  const double* __restrict__ bs = ws + OFF_BS;
  const int tid = threadIdx.x;
  const int nl = tid >> 7, lane = tid & 127;
  const int m0 = blockIdx.x << 1;
  const int m = m0 + nl;
  // B1: stage h; x = [ie | te]
  hbuf[nl][lane] = h[(size_t)m*RCH + lane];
  if (lane < 64) {
    double teacc = (double)b_tensor[lane];
    for (int pc = 0; pc < KSPLIT; ++pc)
      teacc += part[((size_t)pc*NNODE + m)*ECH + lane];
    xbuf[nl][64+lane] = fmax(teacc, 0.0);
  } else {
    int e = lane - 64;
    double n0v = (double)nodes[((size_t)t*NNODE + m)*ICH + 0];
    double n1v = (double)nodes[((size_t)t*NNODE + m)*ICH + 1];
    double ie = n0v*(double)W_in[e*2] + n1v*(double)W_in[e*2+1] + (double)b_in[e];
    xbuf[nl][e] = fmax(ie, 0.0);
  }
  __syncthreads();
  // B2: gates for r=lane (i,f,g,o packed per (p,r))
  const int r = lane;
  double a0=0, a1=0, a2=0, a3=0;
  const double* wgp = WgT + ((size_t)r << 2);
  const double* whp = WhT + ((size_t)r << 2);
  #pragma unroll 2
  for (int p = 0; p < 128; ++p) {
    double xv = xbuf[nl][p], hv = hbuf[nl][p];
    double2 g01 = *(const double2*)(wgp + ((size_t)p << 9));
    double2 g23 = *(const double2*)(wgp + ((size_t)p << 9) + 2);
    double2 q01 = *(const double2*)(whp + ((size_t)p << 9));
    double2 q23 = *(const double2*)(whp + ((size_t)p << 9) + 2);
    a0 += xv*g01.x + hv*q01.x;
    a1 += xv*g01.y + hv*q01.y;
    a2 += xv*g23.x + hv*q23.x;
    a3 += xv*g23.y + hv*q23.y;
  }
  double ig = sigd(a0 + bs[(r<<2)+0]);
  double fg = sigd(a1 + bs[(r<<2)+1]);
  double gg = tanh(a2 + bs[(r<<2)+2]);
  double og = sigd(a3 + bs[(r<<2)+3]);
  double cold = c[(size_t)m*RCH + r];
  double c2 = fg*cold + ig*gg;
  double h2 = og*tanh(c2);
  c[(size_t)m*RCH + r] = c2;
  h[(size_t)m*RCH + r] = h2;
  h2buf[nl][r] = h2;
  if (t == TT-1) {
    hf[(size_t)m*RCH + r] = (float)h2;
    cf[(size_t)m*RCH + r] = (float)c2;
  }
  __syncthreads();
  // B3: out[t][m][oo] — waves 0/2 handle node 0/1
  const int w = tid >> 6;
  if ((w & 1) == 0) {
    const int node = w >> 1, l = tid & 63;
    #pragma unroll
    for (int oo = 0; oo < OCH; ++oo) {
      double v = h2buf[node][l]*(double)W_out[oo*RCH + l]
               + h2buf[node][64+l]*(double)W_out[oo*RCH + 64 + l];
      for (int off = 32; off > 0; off >>= 1) v += __shfl_down(v, off, 64);
      if (l == 0)
        outp[((size_t)t*NNODE + m0 + node)*OCH + oo] = (float)(v + (double)b_out[oo]);
    }
  }
  // B4: Ht for next step from fresh h2
  if (t < TT-1) {
    const int e = tid & 63, gq = tid >> 6;
    double acc[2][4] = {};
    for (int rr = 0; rr < 128; ++rr) {
      double hv0 = h2buf[0][rr], hv1 = h2buf[1][rr];
      #pragma unroll
      for (int jg = 0; jg < 4; ++jg) {
        double wv = WtT[((size_t)(((gq<<2)+jg)*RCH + rr))*ECH + e];
        acc[0][jg] += hv0*wv; acc[1][jg] += hv1*wv;
      }
    }
    #pragma unroll
    for (int n2 = 0; n2 < 2; ++n2)
      #pragma unroll
      for (int jg = 0; jg < 4; ++jg)
        Ht[(((size_t)(m0+n2))*G2C + (gq<<2)+jg)*ECH + e] = acc[n2][jg];
  }
}

extern "C" void kernel_launch(void* const* d_in, const int* in_sizes, int n_in,
                              void* d_out, int out_size, void* d_ws, size_t ws_size,
                              hipStream_t stream) {
  const float* nodes    = (const float*)d_in[0];
  const float* grids    = (const float*)d_in[1];
  const float* h0       = (const float*)d_in[2];
  const float* c0       = (const float*)d_in[3];
  const float* W_in     = (const float*)d_in[4];
  const float* b_in     = (const float*)d_in[5];
  const float* W_tensor = (const float*)d_in[6];
  const float* b_tensor = (const float*)d_in[7];
  const float* W_ih     = (const float*)d_in[8];
  const float* b_ih     = (const float*)d_in[9];
  const float* W_hh     = (const float*)d_in[10];
  const float* b_hh     = (const float*)d_in[11];
  const float* W_out    = (const float*)d_in[12];
  const float* b_out    = (const float*)d_in[13];
  double* ws = (double*)d_ws;
  float* outp = (float*)d_out;                 // [20][512][5]
  float* hf = outp + (size_t)TT*NNODE*OCH;     // [512][128]
  float* cf = hf + (size_t)NNODE*RCH;          // [512][128]

  k_init<<<256, 256, 0, stream>>>(h0, c0, W_ih, b_ih, W_hh, b_hh, W_tensor, ws);
  k_ht<<<256, 256, 0, stream>>>(ws);
  for (int t = 0; t < TT; ++t) {
    k_social<<<512, 256, 0, stream>>>(grids, ws, t);
    k_cell<<<256, 256, 0, stream>>>(nodes, W_in, b_in, b_tensor, W_out, b_out,
                                    ws, outp, hf, cf, t);
  }
}

// Round 3
// 1396.908 us; speedup vs baseline: 1.2334x; 1.2334x over previous
//
#include <hip/hip_runtime.h>

// Problem constants
#define TT 20
#define NNODE 512
#define G2C 16
#define RCH 128
#define ECH 64
#define ICH 2
#define OCH 5
#define KSOC 8192          // N*G2
#define KSPLIT 16
#define KCH 512            // KSOC/KSPLIT
#define SGS 516            // LDS f32 row stride in k_social (516%8==4 -> conflict-free)

// workspace layout (double offsets)
#define OFF_H    0u         // h   [512*128]
#define OFF_C    65536u     // c   [512*128]
#define OFF_HT   131072u    // Ht  [8192][64]
#define OFF_PART 655360u    // part[16][512][64]
#define OFF_WCAT 1179648u   // Wcat[512 gc][256 kk] (kk<128: W_ih, kk>=128: W_hh)
#define OFF_WTT  1310720u   // WtT [2048 q2][64 e]  q2 = g*128+r
#define OFF_BS   1441792u   // bs  [512 gc]
// total 1442304 doubles = 11.54 MB

__device__ __forceinline__ double sigd(double x){ return 1.0/(1.0+exp(-x)); }

__global__ void k_init(const float* __restrict__ h0, const float* __restrict__ c0,
                       const float* __restrict__ W_ih, const float* __restrict__ b_ih,
                       const float* __restrict__ W_hh, const float* __restrict__ b_hh,
                       const float* __restrict__ W_tensor, double* __restrict__ ws) {
  int tid = blockIdx.x*blockDim.x + threadIdx.x;
  int nthr = gridDim.x*blockDim.x;
  double* h = ws + OFF_H; double* c = ws + OFF_C;
  double* Wcat = ws + OFF_WCAT; double* WtT = ws + OFF_WTT;
  double* bs = ws + OFF_BS;
  for (int i = tid; i < NNODE*RCH; i += nthr) { h[i] = (double)h0[i]; c[i] = (double)c0[i]; }
  // Wcat[gc][kk]: kk<128 -> W_ih[gc][kk]; kk>=128 -> W_hh[gc][kk-128]
  for (int i = tid; i < 512*256; i += nthr) {
    int kk = i & 255; int gc = i >> 8;
    Wcat[i] = (kk < 128) ? (double)W_ih[gc*128 + kk] : (double)W_hh[gc*128 + (kk-128)];
  }
  // WtT[q2][e] = W_tensor[e][q2]
  for (int i = tid; i < 2048*64; i += nthr) {
    int e = i & 63; int q2 = i >> 6;
    WtT[i] = (double)W_tensor[e*2048 + q2];
  }
  for (int i = tid; i < 512; i += nthr) bs[i] = (double)b_ih[i] + (double)b_hh[i];
}

// part[kc][n][e] = sum_{k in chunk kc} grid_flat[n,k] * Ht[k,e]
// 512 blocks = 32 n-groups(16 nodes) x 16 k-chunks; 4 waves split the 512-k chunk.
__global__ __launch_bounds__(256) void k_social(const float* __restrict__ grids,
                                                double* __restrict__ ws, int t) {
  __shared__ __align__(16) double sgd[4160];   // alias: f32 grid tile [16][516], then f64 reduce
  float* sgf = (float*)sgd;
  const double* __restrict__ Ht = ws + OFF_HT;
  double* __restrict__ part = ws + OFF_PART;
  const int kc = blockIdx.x & (KSPLIT-1);
  const int n0 = (blockIdx.x >> 4) << 4;
  const int kb = kc * KCH;
  const int tid = threadIdx.x;
  const float* gbase = grids + (size_t)t*NNODE*KSOC;
  for (int i = tid; i < 16*128; i += 256) {
    int row = i >> 7; int c4 = i & 127;
    float4 v = *(const float4*)(gbase + (size_t)(n0+row)*KSOC + kb + (c4<<2));
    *(float4*)(&sgf[row*SGS + (c4<<2)]) = v;
  }
  __syncthreads();
  const int lane = tid & 63;
  const int wv = tid >> 6;
  const int e0 = (lane & 15) << 2;
  const int nq = lane >> 4;
  double acc[4][4] = {};
  const int kl0 = wv << 7;
  const double* htp = Ht + (size_t)(kb + kl0)*ECH + e0;
  #pragma unroll 2
  for (int kk = 0; kk < 128; kk += 2) {
    double2 b0a = *(const double2*)(htp + (size_t)kk*ECH);
    double2 b0b = *(const double2*)(htp + (size_t)kk*ECH + 2);
    double2 b1a = *(const double2*)(htp + (size_t)(kk+1)*ECH);
    double2 b1b = *(const double2*)(htp + (size_t)(kk+1)*ECH + 2);
    const int kl = kl0 + kk;
    #pragma unroll
    for (int jn = 0; jn < 4; ++jn) {
      float2 av2 = *(const float2*)(&sgf[((jn<<2)+nq)*SGS + kl]);
      double a0 = (double)av2.x, a1 = (double)av2.y;
      acc[jn][0] += a0*b0a.x + a1*b1a.x;
      acc[jn][1] += a0*b0a.y + a1*b1a.y;
      acc[jn][2] += a0*b0b.x + a1*b1b.x;
      acc[jn][3] += a0*b0b.y + a1*b1b.y;
    }
  }
  __syncthreads();                 // everyone done reading sgf
  if (wv > 0) {
    double* rp = sgd + ((size_t)(wv-1)*64 + lane)*16;
    #pragma unroll
    for (int jn = 0; jn < 4; ++jn)
      #pragma unroll
      for (int je = 0; je < 4; ++je) rp[(jn<<2)+je] = acc[jn][je];
  }
  __syncthreads();
  if (wv == 0) {
    #pragma unroll
    for (int w = 0; w < 3; ++w) {
      const double* rp = sgd + ((size_t)w*64 + lane)*16;
      #pragma unroll
      for (int jn = 0; jn < 4; ++jn)
        #pragma unroll
        for (int je = 0; je < 4; ++je) acc[jn][je] += rp[(jn<<2)+je];
    }
    #pragma unroll
    for (int jn = 0; jn < 4; ++jn) {
      double* pp = part + ((size_t)kc*NNODE + n0 + (jn<<2) + nq)*ECH + e0;
      pp[0]=acc[jn][0]; pp[1]=acc[jn][1]; pp[2]=acc[jn][2]; pp[3]=acc[jn][3];
    }
  }
}

// Gates + LSTM pointwise. 512 blocks = 32 n-chunks(16 nodes) x 16 r-chunks(8 r, all 4 gates).
__global__ __launch_bounds__(256) void k_cell(const float* __restrict__ nodes,
    const float* __restrict__ W_in, const float* __restrict__ b_in,
    const float* __restrict__ b_tensor,
    double* __restrict__ ws, float* __restrict__ hf, float* __restrict__ cf, int t) {
  __shared__ double xh[16][258];    // [n][kk] kk<64 ie | 64..127 te | 128..255 h
  __shared__ double gbuf[32][17];   // [j = q*8+jr][n]
  double* __restrict__ h = ws + OFF_H;
  double* __restrict__ c = ws + OFF_C;
  const double* __restrict__ part = ws + OFF_PART;
  const double* __restrict__ Wcat = ws + OFF_WCAT;
  const double* __restrict__ bs = ws + OFF_BS;
  const int tid = threadIdx.x;
  const int nc = blockIdx.x >> 4;
  const int rc = blockIdx.x & 15;
  const int m0 = nc << 4;
  // stage x = [ie|te]
  {
    const int e = tid & 63;
    #pragma unroll
    for (int pass = 0; pass < 4; ++pass) {
      const int n = (tid >> 6) + (pass << 2);
      const int m = m0 + n;
      double te = (double)b_tensor[e];
      for (int kc = 0; kc < KSPLIT; ++kc)
        te += part[((size_t)kc*NNODE + m)*ECH + e];
      double n0v = (double)nodes[((size_t)t*NNODE + m)*ICH + 0];
      double n1v = (double)nodes[((size_t)t*NNODE + m)*ICH + 1];
      double ie = n0v*(double)W_in[e*2] + n1v*(double)W_in[e*2+1] + (double)b_in[e];
      xh[n][e] = fmax(ie, 0.0);
      xh[n][64+e] = fmax(te, 0.0);
    }
    const int r = tid & 127;
    #pragma unroll
    for (int pass = 0; pass < 8; ++pass) {
      const int n = (tid >> 7) + (pass << 1);
      xh[n][128+r] = h[(size_t)(m0+n)*RCH + r];
    }
  }
  __syncthreads();
  // MAC: thread = (n, tg); gate cols j0=tg, j1=tg+16
  {
    const int n = tid & 15, tg = tid >> 4;
    const int q0 = tg >> 3, jr = tg & 7;
    const int gc0 = q0*128 + rc*8 + jr;
    const int gc1 = (q0+2)*128 + rc*8 + jr;
    const double* w0 = Wcat + (size_t)gc0*256;
    const double* w1 = Wcat + (size_t)gc1*256;
    double a0 = 0.0, a1 = 0.0;
    #pragma unroll 8
    for (int kk = 0; kk < 256; kk += 2) {
      double2 xv = *(const double2*)(&xh[n][kk]);
      double2 wa = *(const double2*)(w0 + kk);
      double2 wb = *(const double2*)(w1 + kk);
      a0 += xv.x*wa.x + xv.y*wa.y;
      a1 += xv.x*wb.x + xv.y*wb.y;
    }
    gbuf[tg][n]    = a0 + bs[gc0];
    gbuf[tg+16][n] = a1 + bs[gc1];
  }
  __syncthreads();
  // pointwise: 128 threads = 16 n x 8 jr
  if (tid < 128) {
    const int n = tid >> 3, jr = tid & 7;
    const int m = m0 + n, r = rc*8 + jr;
    double ig = sigd(gbuf[jr][n]);
    double fg = sigd(gbuf[8+jr][n]);
    double gg = tanh(gbuf[16+jr][n]);
    double og = sigd(gbuf[24+jr][n]);
    double cold = c[(size_t)m*RCH + r];
    double c2 = fg*cold + ig*gg;
    double h2v = og*tanh(c2);
    c[(size_t)m*RCH + r] = c2;
    h[(size_t)m*RCH + r] = h2v;
    if (t == TT-1) {
      hf[(size_t)m*RCH + r] = (float)h2v;
      cf[(size_t)m*RCH + r] = (float)c2;
    }
  }
}

// Ht[m*16+g][e] = sum_r h[m,r]*WtT[g*128+r][e]; plus out for g-chunk-0 blocks.
// 256 blocks = 32 m-chunks(16) x 8 g-chunks(2 g).
__global__ __launch_bounds__(256) void k_ht_out(const float* __restrict__ W_out,
    const float* __restrict__ b_out, double* __restrict__ ws,
    float* __restrict__ outp, int t, int wout) {
  __shared__ double h2b[16][130];
  const double* __restrict__ h = ws + OFF_H;
  const double* __restrict__ WtT = ws + OFF_WTT;
  double* __restrict__ Ht = ws + OFF_HT;
  const int tid = threadIdx.x;
  const int mc = blockIdx.x >> 3;
  const int gc2 = blockIdx.x & 7;
  const int m0 = mc << 4, g0 = gc2 << 1;
  {
    const int r = tid & 127;
    #pragma unroll
    for (int pass = 0; pass < 8; ++pass) {
      const int n = (tid >> 7) + (pass << 1);
      h2b[n][r] = h[(size_t)(m0+n)*RCH + r];
    }
  }
  __syncthreads();
  // thread = (mh 0..3, e); owns 4 m x 2 g
  {
    const int e = tid & 63, mh = tid >> 6;
    const double* wt0 = WtT + (size_t)(g0*128)*ECH + e;
    const double* wt1 = WtT + (size_t)((g0+1)*128)*ECH + e;
    double acc[4][2] = {};
    #pragma unroll 4
    for (int rr = 0; rr < 128; ++rr) {
      double w0 = wt0[(size_t)rr*ECH];
      double w1 = wt1[(size_t)rr*ECH];
      #pragma unroll
      for (int mi = 0; mi < 4; ++mi) {
        double hv = h2b[(mh<<2)+mi][rr];
        acc[mi][0] += hv*w0;
        acc[mi][1] += hv*w1;
      }
    }
    #pragma unroll
    for (int mi = 0; mi < 4; ++mi) {
      const int m = m0 + (mh<<2) + mi;
      Ht[((size_t)m*G2C + g0    )*ECH + e] = acc[mi][0];
      Ht[((size_t)m*G2C + g0 + 1)*ECH + e] = acc[mi][1];
    }
  }
  // out for this m-chunk (one g-chunk does it)
  if (gc2 == 0 && wout && tid < 80) {
    const int mi = tid / OCH, oo = tid % OCH;
    double v = (double)b_out[oo];
    for (int r = 0; r < 128; ++r)
      v += h2b[mi][r]*(double)W_out[oo*RCH + r];
    outp[((size_t)t*NNODE + m0 + mi)*OCH + oo] = (float)v;
  }
}

extern "C" void kernel_launch(void* const* d_in, const int* in_sizes, int n_in,
                              void* d_out, int out_size, void* d_ws, size_t ws_size,
                              hipStream_t stream) {
  const float* nodes    = (const float*)d_in[0];
  const float* grids    = (const float*)d_in[1];
  const float* h0       = (const float*)d_in[2];
  const float* c0       = (const float*)d_in[3];
  const float* W_in     = (const float*)d_in[4];
  const float* b_in     = (const float*)d_in[5];
  const float* W_tensor = (const float*)d_in[6];
  const float* b_tensor = (const float*)d_in[7];
  const float* W_ih     = (const float*)d_in[8];
  const float* b_ih     = (const float*)d_in[9];
  const float* W_hh     = (const float*)d_in[10];
  const float* b_hh     = (const float*)d_in[11];
  const float* W_out    = (const float*)d_in[12];
  const float* b_out    = (const float*)d_in[13];
  double* ws = (double*)d_ws;
  float* outp = (float*)d_out;                 // [20][512][5]
  float* hf = outp + (size_t)TT*NNODE*OCH;     // [512][128]
  float* cf = hf + (size_t)NNODE*RCH;          // [512][128]

  k_init<<<256, 256, 0, stream>>>(h0, c0, W_ih, b_ih, W_hh, b_hh, W_tensor, ws);
  k_ht_out<<<256, 256, 0, stream>>>(W_out, b_out, ws, outp, 0, 0);   // Ht from h(0)
  for (int t = 0; t < TT; ++t) {
    k_social<<<512, 256, 0, stream>>>(grids, ws, t);
    k_cell<<<512, 256, 0, stream>>>(nodes, W_in, b_in, b_tensor, ws, hf, cf, t);
    k_ht_out<<<256, 256, 0, stream>>>(W_out, b_out, ws, outp, t, 1); // Ht(t+1) + out[t]
  }
}